// Round 9
// baseline (172.695 us; speedup 1.0000x reference)
//
#include <hip/hip_runtime.h>
#include <hip/hip_bf16.h>
#include <math.h>

#define NTOK 1024
#define DIN  512
#define NF   4
#define DCOND 128
#define H    8
#define HD   64
#define NQKV 1536
#define LOG2E 1.4426950408889634f

typedef __attribute__((ext_vector_type(8))) short bf16x8;
typedef __attribute__((ext_vector_type(4))) float f32x4;
typedef __attribute__((ext_vector_type(4))) unsigned short us4;

__device__ __forceinline__ unsigned short f2b(float f) {
  union { float f; unsigned int u; } v; v.f = f;
  unsigned int r = v.u + 0x7fffu + ((v.u >> 16) & 1u);
  return (unsigned short)(r >> 16);
}

__device__ __forceinline__ float b2f(unsigned short h) {
  union { unsigned int u; float f; } v; v.u = ((unsigned int)h) << 16;
  return v.f;
}

__device__ __forceinline__ float asf(unsigned int u) {
  union { unsigned int u; float f; } v; v.u = u;
  return v.f;
}

__device__ __forceinline__ void gl_lds16(const void* g, void* l) {
  __builtin_amdgcn_global_load_lds(
      (const __attribute__((address_space(1))) unsigned int*)g,
      (__attribute__((address_space(3))) unsigned int*)l, 16, 0, 0);
}

// ---------------- prep_a: W converts + matvec tmp = (w_c@code) ----------------
__global__ void prep_a(const float* __restrict__ W_qkv, const float* __restrict__ W_proj,
                       const float* __restrict__ w_c, const float* __restrict__ code,
                       unsigned short* __restrict__ Wqh, unsigned short* __restrict__ Wph,
                       float* __restrict__ tmpv) {
  const int bid = blockIdx.x, tid = threadIdx.x;
  if (bid < 256) {
    const float* src; unsigned short* dst; int e;
    if (bid < 192) { src = W_qkv; dst = Wqh; e = bid * 4096 + tid * 16; }
    else { src = W_proj; dst = Wph; e = (bid - 192) * 4096 + tid * 16; }
#pragma unroll
    for (int j = 0; j < 4; ++j) {
      float4 a = *reinterpret_cast<const float4*>(&src[e + j * 4]);
      us4 p = { f2b(a.x), f2b(a.y), f2b(a.z), f2b(a.w) };
      *reinterpret_cast<us4*>(&dst[e + j * 4]) = p;
    }
  } else {
    // matvec: 64 rows/block, 4 threads per row (one per f)
    int i = (bid - 256) * 64 + (tid >> 2);
    int f = tid & 3;
    const float* wr = w_c + i * DCOND;
    float acc = 0.f;
#pragma unroll 16
    for (int k = 0; k < DCOND; ++k) acc += wr[k] * code[k * NF + f];
    tmpv[f * DIN + i] = acc;
  }
}

// ---------------- ln2: LN over tmp rows -> cmq, cmp_ ----------------
__global__ void ln2_kernel(const float* __restrict__ tmpv,
                           const float* __restrict__ lnqg, const float* __restrict__ lnqb,
                           const float* __restrict__ lnpg, const float* __restrict__ lnpb,
                           float* __restrict__ cmq, float* __restrict__ cmp_) {
  const int i = threadIdx.x;          // 0..511
  const int w = i >> 6, lane = i & 63;
  float t[NF];
#pragma unroll
  for (int f = 0; f < NF; ++f) t[f] = tmpv[f * DIN + i];
  __shared__ float redS[8], redQ[8];
#pragma unroll
  for (int f = 0; f < NF; ++f) {
    float s = t[f], q = t[f] * t[f];
#pragma unroll
    for (int o = 32; o > 0; o >>= 1) { s += __shfl_xor(s, o); q += __shfl_xor(q, o); }
    if (lane == 0) { redS[w] = s; redQ[w] = q; }
    __syncthreads();
    float S = 0.f, Q = 0.f;
#pragma unroll
    for (int j = 0; j < 8; ++j) { S += redS[j]; Q += redQ[j]; }
    float mu = S * (1.f / 512.f);
    float var = Q * (1.f / 512.f) - mu * mu;
    float rstd = rsqrtf(var + 1e-5f);
    float nv = (t[f] - mu) * rstd;
    cmq[f * DIN + i]  = nv * lnqg[i] + lnqb[i];
    cmp_[f * DIN + i] = nv * lnpg[i] + lnpb[i];
    __syncthreads();
  }
}

// ---------------- prep_b: xm = bf16(x*cmq) ----------------
__global__ void prep_b(const float* __restrict__ x, const float* __restrict__ cmq,
                       unsigned short* __restrict__ xm) {
  int e = blockIdx.x * 4096 + threadIdx.x * 16;   // [4][1024][512] flat
  int row = e >> 9, d = e & 511;
  int f = row >> 10, n = row & 1023;
  const float* xr = x + (size_t)n * DIN + d;
  const float* cr = cmq + f * DIN + d;
#pragma unroll
  for (int j = 0; j < 4; ++j) {
    float4 a = *reinterpret_cast<const float4*>(xr + j * 4);
    float4 c = *reinterpret_cast<const float4*>(cr + j * 4);
    us4 p = { f2b(a.x * c.x), f2b(a.y * c.y), f2b(a.z * c.z), f2b(a.w * c.w) };
    *reinterpret_cast<us4*>(&xm[e + j * 4]) = p;
  }
}

// ---------------- bf16 GEMM, 64x64 tile ----------------
template<int NCOL, bool OUT_BF16, bool WRITE_VT, bool SCALE_Q>
__global__ __launch_bounds__(256, 6)
void gemm64(const unsigned short* __restrict__ Ah,   // [4096][512]
            const unsigned short* __restrict__ Wh,   // [NCOL][512]
            const float* __restrict__ bias,
            unsigned short* __restrict__ outH,
            float* __restrict__ outF,
            unsigned short* __restrict__ vT) {
  __shared__ __align__(16) unsigned short sA[2][2048];
  __shared__ __align__(16) unsigned short sB[2][2048];
  const int tid = threadIdx.x;
  const int lane = tid & 63, w = tid >> 6;
  const int li = lane & 15, g = lane >> 4;
  const int wr = (w >> 1) * 32, wc = (w & 1) * 32;
  const int row0 = blockIdx.y * 64, col0 = blockIdx.x * 64;
  const int f = row0 >> 10;
  const int sr = tid >> 2, sp = tid & 3;
  const int ss = sp ^ ((sr >> 1) & 3);

  f32x4 acc[2][2];
#pragma unroll
  for (int m = 0; m < 2; ++m)
#pragma unroll
    for (int n = 0; n < 2; ++n) acc[m][n] = (f32x4){0.f, 0.f, 0.f, 0.f};

  const unsigned short* aSrc = Ah + (size_t)(row0 + sr) * DIN + ss * 8;
  const unsigned short* bSrc = Wh + (size_t)(col0 + sr) * DIN + ss * 8;

  gl_lds16(aSrc, &sA[0][w * 512]);
  gl_lds16(bSrc, &sB[0][w * 512]);
  __syncthreads();
  for (int it = 0; it < 16; ++it) {
    int buf = it & 1;
    if (it < 15) {
      gl_lds16(aSrc + (it + 1) * 32, &sA[buf ^ 1][w * 512]);
      gl_lds16(bSrc + (it + 1) * 32, &sB[buf ^ 1][w * 512]);
    }
    bf16x8 aF[2], bF[2];
#pragma unroll
    for (int m = 0; m < 2; ++m) {
      int ra = wr + m * 16 + li;
      aF[m] = *reinterpret_cast<const bf16x8*>(&sA[buf][(ra * 4 + (g ^ ((ra >> 1) & 3))) * 8]);
    }
#pragma unroll
    for (int n = 0; n < 2; ++n) {
      int cb = wc + n * 16 + li;
      bF[n] = *reinterpret_cast<const bf16x8*>(&sB[buf][(cb * 4 + (g ^ ((cb >> 1) & 3))) * 8]);
    }
#pragma unroll
    for (int m = 0; m < 2; ++m)
#pragma unroll
      for (int n = 0; n < 2; ++n)
        acc[m][n] = __builtin_amdgcn_mfma_f32_16x16x32_bf16(aF[m], bF[n], acc[m][n], 0, 0, 0);
    __syncthreads();
  }
#pragma unroll
  for (int n = 0; n < 2; ++n) {
    int col = col0 + wc + n * 16 + li;
    float bb = bias[col];
    float sc = (SCALE_Q && col < DIN) ? (0.125f * LOG2E) : 1.0f;
#pragma unroll
    for (int m = 0; m < 2; ++m) {
      int rb = row0 + wr + m * 16 + g * 4;
      f32x4 v = acc[m][n];
      if constexpr (OUT_BF16) {
        if (WRITE_VT && col >= 1024) {
          int tok0 = rb & 1023;
          us4 pk;
#pragma unroll
          for (int r = 0; r < 4; ++r) pk[r] = f2b(v[r] + bb);
          *reinterpret_cast<us4*>(&vT[((size_t)(f * 512 + (col - 1024))) * NTOK + tok0]) = pk;
        } else {
#pragma unroll
          for (int r = 0; r < 4; ++r)
            outH[(size_t)(rb + r) * NCOL + col] = f2b((v[r] + bb) * sc);
        }
      } else {
#pragma unroll
        for (int r = 0; r < 4; ++r)
          outF[(size_t)(rb + r) * NCOL + col] = v[r] + bb;
      }
    }
  }
}

// ---------------- MFMA attention v6: LDS comp + stage hidden under softmax+PV ----------------
__global__ __launch_bounds__(512, 4)
void attn_mfma6(const unsigned short* __restrict__ qkvh,  // [4][1024][1536] (Q scaled 0.125*log2e)
                const unsigned short* __restrict__ vTh,   // [4][512][1024] V^T
                const float* __restrict__ comp,           // [4][1024] f32
                const float* __restrict__ cmp_,           // [4][512]
                unsigned short* __restrict__ ym) {        // [4][1024][512] bf16*cmp_
  __shared__ __align__(16) unsigned short sK[2][4096];
  __shared__ __align__(16) unsigned short sV[2][4096];
  __shared__ __align__(16) unsigned short wbuf_all[8][16 * 68];
  __shared__ unsigned int sc01[1024], sc23[1024];
  __shared__ float lred[2][4][16];
  __shared__ float s2red[4][16];
  // total: 16384+16384+17408+8192+512+256 = 59136 B (<64 KiB; 2 blocks/CU)

  const int tid = threadIdx.x, lane = tid & 63, w = tid >> 6;  // 8 waves
  const int li = lane & 15, g = lane >> 4;
  const int rt = w & 3, ch = w >> 2;
  const int hf = blockIdx.x, qt = blockIdx.y;
  const int h = hf >> 2, f = hf & 3;

  {
    int c = tid * 2;
    float2 a0 = *reinterpret_cast<const float2*>(&comp[c]);
    float2 a1 = *reinterpret_cast<const float2*>(&comp[1024 + c]);
    float2 a2 = *reinterpret_cast<const float2*>(&comp[2048 + c]);
    float2 a3 = *reinterpret_cast<const float2*>(&comp[3072 + c]);
    sc01[c]     = f2b(a0.x) | ((unsigned int)f2b(a1.x) << 16);
    sc01[c + 1] = f2b(a0.y) | ((unsigned int)f2b(a1.y) << 16);
    sc23[c]     = f2b(a2.x) | ((unsigned int)f2b(a3.x) << 16);
    sc23[c + 1] = f2b(a2.y) | ((unsigned int)f2b(a3.y) << 16);
  }

  const int qrow0 = qt * 64 + rt * 16;
  const unsigned short* qbase = qkvh + ((size_t)(f * NTOK + qrow0 + li)) * NQKV + h * HD;
  bf16x8 aq[2];
  aq[0] = *reinterpret_cast<const bf16x8*>(qbase + g * 8);
  aq[1] = *reinterpret_cast<const bf16x8*>(qbase + 32 + g * 8);

  float crow[4][4];
#pragma unroll
  for (int ff = 0; ff < 4; ++ff)
#pragma unroll
    for (int r = 0; r < 4; ++r)
      crow[ff][r] = comp[ff * NTOK + qrow0 + g * 4 + r];

  const unsigned short* kb = qkvh + ((size_t)(f * NTOK)) * NQKV + DIN + h * HD;
  const unsigned short* vb = vTh + ((size_t)(f * DIN + h * HD)) * NTOK;

  const int remK = w * 64 + lane;
  const int ktok = remK >> 3, kdg = remK & 7;
  const int ksw = kdg ^ (ktok & 7);

  auto stageK_to = [&](unsigned short (*dst)[4096], int s) {
#pragma unroll
    for (int j = 0; j < 2; ++j) {
      int tokg = j * 512 + s * 64 + ktok;
      gl_lds16(kb + (size_t)tokg * NQKV + ksw * 8, &dst[j][(w * 64) * 8]);
    }
  };
  auto stageV_to = [&](int s) {
#pragma unroll
    for (int j = 0; j < 2; ++j) {
      int d = ktok, tg = kdg;
      int sw = tg ^ (d & 7);
      gl_lds16(vb + (size_t)d * NTOK + j * 512 + s * 64 + sw * 8, &sV[j][(w * 64) * 8]);
    }
  };

  // ---- pass A: lsum = sum(exp2(S')) over this wave's col half (ping-pong dbuf, proven R7) ----
  float lsum[4] = {0.f, 0.f, 0.f, 0.f};
  stageK_to(sK, 0);
  __syncthreads();
  for (int s = 0; s < 8; ++s) {
    unsigned short (*cur)[4096] = (s & 1) ? sV : sK;
    if (s < 7) stageK_to((s & 1) ? sK : sV, s + 1);
    bf16x8 bk[4][2];
#pragma unroll
    for (int cf = 0; cf < 4; ++cf)
#pragma unroll
      for (int ks = 0; ks < 2; ++ks) {
        int tok = cf * 16 + li, dg = ks * 4 + g;
        bk[cf][ks] = *reinterpret_cast<const bf16x8*>(&cur[ch][(tok * 8 + (dg ^ (tok & 7))) * 8]);
      }
    f32x4 accs[4];
#pragma unroll
    for (int cf = 0; cf < 4; ++cf) accs[cf] = (f32x4){0.f, 0.f, 0.f, 0.f};
#pragma unroll
    for (int ks = 0; ks < 2; ++ks)
#pragma unroll
      for (int cf = 0; cf < 4; ++cf)
        accs[cf] = __builtin_amdgcn_mfma_f32_16x16x32_bf16(aq[ks], bk[cf][ks], accs[cf], 0, 0, 0);
#pragma unroll
    for (int cf = 0; cf < 4; ++cf)
#pragma unroll
      for (int r = 0; r < 4; ++r) lsum[r] += __builtin_amdgcn_exp2f(accs[cf][r]);
    __syncthreads();
  }
#pragma unroll
  for (int r = 0; r < 4; ++r) {
    lsum[r] += __shfl_xor(lsum[r], 1);
    lsum[r] += __shfl_xor(lsum[r], 2);
    lsum[r] += __shfl_xor(lsum[r], 4);
    lsum[r] += __shfl_xor(lsum[r], 8);
  }
  if (li == 0) {
#pragma unroll
    for (int r = 0; r < 4; ++r) lred[ch][rt][g * 4 + r] = lsum[r];
  }
  __syncthreads();
  float invl[4];
#pragma unroll
  for (int r = 0; r < 4; ++r)
    invl[r] = LOG2E / (lred[0][rt][g * 4 + r] + lred[1][rt][g * 4 + r]);

  // ---- pass B: t = exp2((exp2(S')*invl)*cc), PV + sum2; stage hidden under softmax+PV ----
  f32x4 acco[4];
  float sum2[4] = {0.f, 0.f, 0.f, 0.f};
#pragma unroll
  for (int cf = 0; cf < 4; ++cf) acco[cf] = (f32x4){0.f, 0.f, 0.f, 0.f};
  unsigned short* wb = wbuf_all[w];

  stageK_to(sK, 0);
  stageV_to(0);
  __syncthreads();
  for (int s = 0; s < 8; ++s) {
    // read K operands + QK^T, read V operands into regs (all LDS reads of this tile)
    bf16x8 bk[4][2];
#pragma unroll
    for (int cf = 0; cf < 4; ++cf)
#pragma unroll
      for (int ks = 0; ks < 2; ++ks) {
        int tok = cf * 16 + li, dg = ks * 4 + g;
        bk[cf][ks] = *reinterpret_cast<const bf16x8*>(&sK[ch][(tok * 8 + (dg ^ (tok & 7))) * 8]);
      }
    f32x4 accs[4];
#pragma unroll
    for (int cf = 0; cf < 4; ++cf) accs[cf] = (f32x4){0.f, 0.f, 0.f, 0.f};
#pragma unroll
    for (int ks = 0; ks < 2; ++ks)
#pragma unroll
      for (int cf = 0; cf < 4; ++cf)
        accs[cf] = __builtin_amdgcn_mfma_f32_16x16x32_bf16(aq[ks], bk[cf][ks], accs[cf], 0, 0, 0);
    bf16x8 bv[4][2];
#pragma unroll
    for (int cf = 0; cf < 4; ++cf)
#pragma unroll
      for (int ks = 0; ks < 2; ++ks) {
        int d = cf * 16 + li, tg = ks * 4 + g;
        bv[cf][ks] = *reinterpret_cast<const bf16x8*>(&sV[ch][(d * 8 + (tg ^ (d & 7))) * 8]);
      }
    __syncthreads();                              // all block reads of sK/sV done
    if (s < 7) { stageK_to(sK, s + 1); stageV_to(s + 1); }  // in flight under softmax+PV (no VMEM below)
#pragma unroll
    for (int cf = 0; cf < 4; ++cf) {
      int colg = ch * 512 + s * 64 + cf * 16 + li;
      unsigned int u01 = sc01[colg], u23 = sc23[colg];
      float c0 = asf(u01 << 16), c1 = asf(u01 & 0xffff0000u);
      float c2 = asf(u23 << 16), c3 = asf(u23 & 0xffff0000u);
#pragma unroll
      for (int r = 0; r < 4; ++r) {
        float e = __builtin_amdgcn_exp2f(accs[cf][r]);
        float a = e * invl[r];
        float cc = crow[0][r] * c0 + crow[1][r] * c1 + crow[2][r] * c2 + crow[3][r] * c3;
        float tv = __builtin_amdgcn_exp2f(a * cc);
        unsigned short hv = f2b(tv);
        sum2[r] += b2f(hv);
        wb[(g * 4 + r) * 68 + cf * 16 + li] = hv;
      }
    }
    bf16x8 aw[2];
#pragma unroll
    for (int ks = 0; ks < 2; ++ks)
      aw[ks] = *reinterpret_cast<const bf16x8*>(&wb[li * 68 + ks * 32 + g * 8]);
#pragma unroll
    for (int ks = 0; ks < 2; ++ks)
#pragma unroll
      for (int cf = 0; cf < 4; ++cf)
        acco[cf] = __builtin_amdgcn_mfma_f32_16x16x32_bf16(aw[ks], bv[cf][ks], acco[cf], 0, 0, 0);
    __syncthreads();                              // staged tile s+1 visible (vmcnt drained)
  }

  // ---- combine across ch, write ym ----
#pragma unroll
  for (int r = 0; r < 4; ++r) {
    sum2[r] += __shfl_xor(sum2[r], 1);
    sum2[r] += __shfl_xor(sum2[r], 2);
    sum2[r] += __shfl_xor(sum2[r], 4);
    sum2[r] += __shfl_xor(sum2[r], 8);
  }
  float* fred = (float*)sK;  // 16 KB reuse
  __syncthreads();
  if (ch == 1) {
    if (li == 0) {
#pragma unroll
      for (int r = 0; r < 4; ++r) s2red[rt][g * 4 + r] = sum2[r];
    }
#pragma unroll
    for (int cf = 0; cf < 4; ++cf)
#pragma unroll
      for (int r = 0; r < 4; ++r)
        fred[rt * 1024 + (g * 4 + r) * 64 + cf * 16 + li] = acco[cf][r];
  }
  __syncthreads();
  if (ch == 0) {
    float invs[4];
#pragma unroll
    for (int r = 0; r < 4; ++r) invs[r] = 1.f / (sum2[r] + s2red[rt][g * 4 + r]);
    float cscale[4];
#pragma unroll
    for (int cf = 0; cf < 4; ++cf) cscale[cf] = cmp_[f * DIN + h * HD + cf * 16 + li];
#pragma unroll
    for (int cf = 0; cf < 4; ++cf)
#pragma unroll
      for (int r = 0; r < 4; ++r) {
        float v = (acco[cf][r] + fred[rt * 1024 + (g * 4 + r) * 64 + cf * 16 + li]) * invs[r];
        int qrow = qrow0 + g * 4 + r;
        ym[((size_t)(f * NTOK + qrow)) * DIN + h * HD + cf * 16 + li] = f2b(v * cscale[cf]);
      }
  }
}

extern "C" void kernel_launch(void* const* d_in, const int* in_sizes, int n_in,
                              void* d_out, int out_size, void* d_ws, size_t ws_size,
                              hipStream_t stream) {
  const float* x      = (const float*)d_in[0];
  const float* compat = (const float*)d_in[1];
  const float* code   = (const float*)d_in[2];
  const float* w_c    = (const float*)d_in[3];
  const float* W_qkv  = (const float*)d_in[4];
  const float* b_qkv  = (const float*)d_in[5];
  const float* W_proj = (const float*)d_in[6];
  const float* b_proj = (const float*)d_in[7];
  const float* lnqg   = (const float*)d_in[8];
  const float* lnqb   = (const float*)d_in[9];
  const float* lnpg   = (const float*)d_in[10];
  const float* lnpb   = (const float*)d_in[11];
  float* out = (float*)d_out;

  float* cmq  = (float*)d_ws;
  float* cmp_ = cmq + NF * DIN;
  unsigned short* Wqh  = (unsigned short*)(cmp_ + NF * DIN);
  unsigned short* Wph  = Wqh + (size_t)NQKV * DIN;
  unsigned short* xm   = Wph + (size_t)DIN * DIN;
  unsigned short* qkvh = xm + (size_t)NF * NTOK * DIN;
  unsigned short* vTh  = qkvh + (size_t)NF * NTOK * NQKV;
  unsigned short* ym   = vTh + (size_t)NF * DIN * NTOK;
  float* tmpv = (float*)(ym + (size_t)NF * NTOK * DIN);

  prep_a<<<264, 256, 0, stream>>>(W_qkv, W_proj, w_c, code, Wqh, Wph, tmpv);
  ln2_kernel<<<1, 512, 0, stream>>>(tmpv, lnqg, lnqb, lnpg, lnpb, cmq, cmp_);
  prep_b<<<512, 256, 0, stream>>>(x, cmq, xm);
  gemm64<NQKV, true, true, true><<<dim3(24, 64), 256, 0, stream>>>(
      xm, Wqh, b_qkv, qkvh, nullptr, vTh);
  attn_mfma6<<<dim3(32, 16), 512, 0, stream>>>(qkvh, vTh, compat, cmp_, ym);
  gemm64<DIN, false, false, false><<<dim3(8, 64), 256, 0, stream>>>(
      ym, Wph, b_proj, nullptr, out, nullptr);
}

// Round 10
// 162.861 us; speedup vs baseline: 1.0604x; 1.0604x over previous
//
#include <hip/hip_runtime.h>
#include <hip/hip_bf16.h>
#include <math.h>

#define NTOK 1024
#define DIN  512
#define NF   4
#define DCOND 128
#define H    8
#define HD   64
#define NQKV 1536
#define LOG2E 1.4426950408889634f

typedef __attribute__((ext_vector_type(8))) short bf16x8;
typedef __attribute__((ext_vector_type(4))) float f32x4;
typedef __attribute__((ext_vector_type(4))) unsigned short us4;

__device__ __forceinline__ unsigned short f2b(float f) {
  union { float f; unsigned int u; } v; v.f = f;
  unsigned int r = v.u + 0x7fffu + ((v.u >> 16) & 1u);
  return (unsigned short)(r >> 16);
}

__device__ __forceinline__ float b2f(unsigned short h) {
  union { unsigned int u; float f; } v; v.u = ((unsigned int)h) << 16;
  return v.f;
}

__device__ __forceinline__ float asf(unsigned int u) {
  union { unsigned int u; float f; } v; v.u = u;
  return v.f;
}

__device__ __forceinline__ void gl_lds16(const void* g, void* l) {
  __builtin_amdgcn_global_load_lds(
      (const __attribute__((address_space(1))) unsigned int*)g,
      (__attribute__((address_space(3))) unsigned int*)l, 16, 0, 0);
}

// ---------------- K1: matvec tmp = (w_c@code) + per-block LN partials ----------------
__global__ void prep_mv(const float* __restrict__ w_c, const float* __restrict__ code,
                        float* __restrict__ tmpv, float* __restrict__ pS,
                        float* __restrict__ pQ) {
  const int bid = blockIdx.x, tid = threadIdx.x;   // 8 x 256
  const int i = bid * 64 + (tid >> 2);
  const int f = tid & 3;
  const float* wr = w_c + i * DCOND;
  float acc = 0.f;
#pragma unroll 8
  for (int k = 0; k < DCOND; k += 4) {
    float4 wv = *reinterpret_cast<const float4*>(wr + k);
    acc += wv.x * code[(k + 0) * NF + f] + wv.y * code[(k + 1) * NF + f]
         + wv.z * code[(k + 2) * NF + f] + wv.w * code[(k + 3) * NF + f];
  }
  tmpv[f * DIN + i] = acc;
  float s = acc, q = acc * acc;
#pragma unroll
  for (int o = 4; o <= 32; o <<= 1) { s += __shfl_xor(s, o); q += __shfl_xor(q, o); }
  __shared__ float rs[4][4], rq[4][4];
  const int w = tid >> 6, lane = tid & 63;
  if (lane < 4) { rs[w][lane] = s; rq[w][lane] = q; }
  __syncthreads();
  if (tid < 4) {
    pS[bid * 4 + tid] = rs[0][tid] + rs[1][tid] + rs[2][tid] + rs[3][tid];
    pQ[bid * 4 + tid] = rq[0][tid] + rq[1][tid] + rq[2][tid] + rq[3][tid];
  }
}

// ---------------- K2: W converts + xm = bf16(x * LN_q(tmp)) + cmp_ = LN_p(tmp) ----------------
__global__ void prep_x(const float* __restrict__ W_qkv, const float* __restrict__ W_proj,
                       const float* __restrict__ x, const float* __restrict__ tmpv,
                       const float* __restrict__ pS, const float* __restrict__ pQ,
                       const float* __restrict__ lnqg, const float* __restrict__ lnqb,
                       const float* __restrict__ lnpg, const float* __restrict__ lnpb,
                       unsigned short* __restrict__ Wqh, unsigned short* __restrict__ Wph,
                       unsigned short* __restrict__ xm, float* __restrict__ cmp_) {
  const int bid = blockIdx.x, tid = threadIdx.x;
  if (bid < 256) {
    const float* src; unsigned short* dst; int e;
    if (bid < 192) { src = W_qkv; dst = Wqh; e = bid * 4096 + tid * 16; }
    else { src = W_proj; dst = Wph; e = (bid - 192) * 4096 + tid * 16; }
#pragma unroll
    for (int j = 0; j < 4; ++j) {
      float4 a = *reinterpret_cast<const float4*>(&src[e + j * 4]);
      us4 p = { f2b(a.x), f2b(a.y), f2b(a.z), f2b(a.w) };
      *reinterpret_cast<us4*>(&dst[e + j * 4]) = p;
    }
  } else if (bid < 768) {
    int e = (bid - 256) * 4096 + tid * 16;   // [4][1024][512] flat
    int row = e >> 9, d = e & 511;
    int f = row >> 10, n = row & 1023;
    float S = 0.f, Q = 0.f;
#pragma unroll
    for (int b = 0; b < 8; ++b) { S += pS[b * 4 + f]; Q += pQ[b * 4 + f]; }
    float mu = S * (1.f / 512.f);
    float rstd = rsqrtf(Q * (1.f / 512.f) - mu * mu + 1e-5f);
    const float* xr = x + (size_t)n * DIN + d;
    const float* tr = tmpv + f * DIN + d;
#pragma unroll
    for (int j = 0; j < 4; ++j) {
      float4 a = *reinterpret_cast<const float4*>(xr + j * 4);
      float4 t = *reinterpret_cast<const float4*>(tr + j * 4);
      float4 g = *reinterpret_cast<const float4*>(&lnqg[d + j * 4]);
      float4 b = *reinterpret_cast<const float4*>(&lnqb[d + j * 4]);
      us4 p = { f2b(a.x * ((t.x - mu) * rstd * g.x + b.x)),
                f2b(a.y * ((t.y - mu) * rstd * g.y + b.y)),
                f2b(a.z * ((t.z - mu) * rstd * g.z + b.z)),
                f2b(a.w * ((t.w - mu) * rstd * g.w + b.w)) };
      *reinterpret_cast<us4*>(&xm[e + j * 4]) = p;
    }
  } else {
    // cmp_ : 2048 elems, one block
    int e = tid * 8;
    int f = e >> 9;
    float S = 0.f, Q = 0.f;
#pragma unroll
    for (int b = 0; b < 8; ++b) { S += pS[b * 4 + f]; Q += pQ[b * 4 + f]; }
    float mu = S * (1.f / 512.f);
    float rstd = rsqrtf(Q * (1.f / 512.f) - mu * mu + 1e-5f);
#pragma unroll
    for (int j = 0; j < 8; ++j) {
      int idx = e + j, i = idx & 511;
      cmp_[idx] = (tmpv[idx] - mu) * rstd * lnpg[i] + lnpb[i];
    }
  }
}

// ---------------- bf16 GEMM, 64x64 tile ----------------
template<int NCOL, bool OUT_BF16, bool WRITE_VT, bool SCALE_Q>
__global__ __launch_bounds__(256, 4)
void gemm64(const unsigned short* __restrict__ Ah,   // [4096][512]
            const unsigned short* __restrict__ Wh,   // [NCOL][512]
            const float* __restrict__ bias,
            unsigned short* __restrict__ outH,
            float* __restrict__ outF,
            unsigned short* __restrict__ vT) {
  __shared__ __align__(16) unsigned short sA[2][2048];
  __shared__ __align__(16) unsigned short sB[2][2048];
  const int tid = threadIdx.x;
  const int lane = tid & 63, w = tid >> 6;
  const int li = lane & 15, g = lane >> 4;
  const int wr = (w >> 1) * 32, wc = (w & 1) * 32;
  const int row0 = blockIdx.y * 64, col0 = blockIdx.x * 64;
  const int f = row0 >> 10;
  const int sr = tid >> 2, sp = tid & 3;
  const int ss = sp ^ ((sr >> 1) & 3);

  f32x4 acc[2][2];
#pragma unroll
  for (int m = 0; m < 2; ++m)
#pragma unroll
    for (int n = 0; n < 2; ++n) acc[m][n] = (f32x4){0.f, 0.f, 0.f, 0.f};

  const unsigned short* aSrc = Ah + (size_t)(row0 + sr) * DIN + ss * 8;
  const unsigned short* bSrc = Wh + (size_t)(col0 + sr) * DIN + ss * 8;

  gl_lds16(aSrc, &sA[0][w * 512]);
  gl_lds16(bSrc, &sB[0][w * 512]);
  __syncthreads();
  for (int it = 0; it < 16; ++it) {
    int buf = it & 1;
    if (it < 15) {
      gl_lds16(aSrc + (it + 1) * 32, &sA[buf ^ 1][w * 512]);
      gl_lds16(bSrc + (it + 1) * 32, &sB[buf ^ 1][w * 512]);
    }
    bf16x8 aF[2], bF[2];
#pragma unroll
    for (int m = 0; m < 2; ++m) {
      int ra = wr + m * 16 + li;
      aF[m] = *reinterpret_cast<const bf16x8*>(&sA[buf][(ra * 4 + (g ^ ((ra >> 1) & 3))) * 8]);
    }
#pragma unroll
    for (int n = 0; n < 2; ++n) {
      int cb = wc + n * 16 + li;
      bF[n] = *reinterpret_cast<const bf16x8*>(&sB[buf][(cb * 4 + (g ^ ((cb >> 1) & 3))) * 8]);
    }
#pragma unroll
    for (int m = 0; m < 2; ++m)
#pragma unroll
      for (int n = 0; n < 2; ++n)
        acc[m][n] = __builtin_amdgcn_mfma_f32_16x16x32_bf16(aF[m], bF[n], acc[m][n], 0, 0, 0);
    __syncthreads();
  }
#pragma unroll
  for (int n = 0; n < 2; ++n) {
    int col = col0 + wc + n * 16 + li;
    float bb = bias[col];
    float sc = (SCALE_Q && col < DIN) ? (0.125f * LOG2E) : 1.0f;
#pragma unroll
    for (int m = 0; m < 2; ++m) {
      int rb = row0 + wr + m * 16 + g * 4;
      f32x4 v = acc[m][n];
      if constexpr (OUT_BF16) {
        if (WRITE_VT && col >= 1024) {
          int tok0 = rb & 1023;
          us4 pk;
#pragma unroll
          for (int r = 0; r < 4; ++r) pk[r] = f2b(v[r] + bb);
          *reinterpret_cast<us4*>(&vT[((size_t)(f * 512 + (col - 1024))) * NTOK + tok0]) = pk;
        } else {
#pragma unroll
          for (int r = 0; r < 4; ++r)
            outH[(size_t)(rb + r) * NCOL + col] = f2b((v[r] + bb) * sc);
        }
      } else {
#pragma unroll
        for (int r = 0; r < 4; ++r)
          outF[(size_t)(rb + r) * NCOL + col] = v[r] + bb;
      }
    }
  }
}

// ---------------- MFMA attention v4 (exact R7 revert — proven 47 us) ----------------
__global__ __launch_bounds__(512, 4)
void attn_mfma4(const unsigned short* __restrict__ qkvh,  // [4][1024][1536] (Q scaled 0.125*log2e)
                const unsigned short* __restrict__ vTh,   // [4][512][1024] V^T
                const float* __restrict__ comp,           // [4][1024]
                const float* __restrict__ cmp_,           // [4][512]
                unsigned short* __restrict__ ym) {        // [4][1024][512] bf16*cmp_
  __shared__ __align__(16) unsigned short sK[2][4096];
  __shared__ __align__(16) unsigned short sV[2][4096];
  __shared__ __align__(16) unsigned short wbuf_all[8][16 * 68];
  __shared__ unsigned int sc01[1024], sc23[1024];
  __shared__ float lred[2][4][16];
  __shared__ float s2red[4][16];

  const int tid = threadIdx.x, lane = tid & 63, w = tid >> 6;  // 8 waves
  const int li = lane & 15, g = lane >> 4;
  const int rt = w & 3, ch = w >> 2;
  const int hf = blockIdx.x, qt = blockIdx.y;
  const int h = hf >> 2, f = hf & 3;

  {
    int c = tid * 2;
    float2 a0 = *reinterpret_cast<const float2*>(&comp[c]);
    float2 a1 = *reinterpret_cast<const float2*>(&comp[1024 + c]);
    float2 a2 = *reinterpret_cast<const float2*>(&comp[2048 + c]);
    float2 a3 = *reinterpret_cast<const float2*>(&comp[3072 + c]);
    sc01[c]     = f2b(a0.x) | ((unsigned int)f2b(a1.x) << 16);
    sc01[c + 1] = f2b(a0.y) | ((unsigned int)f2b(a1.y) << 16);
    sc23[c]     = f2b(a2.x) | ((unsigned int)f2b(a3.x) << 16);
    sc23[c + 1] = f2b(a2.y) | ((unsigned int)f2b(a3.y) << 16);
  }

  const int qrow0 = qt * 64 + rt * 16;
  const unsigned short* qbase = qkvh + ((size_t)(f * NTOK + qrow0 + li)) * NQKV + h * HD;
  bf16x8 aq[2];
  aq[0] = *reinterpret_cast<const bf16x8*>(qbase + g * 8);
  aq[1] = *reinterpret_cast<const bf16x8*>(qbase + 32 + g * 8);

  float crow[4][4];
#pragma unroll
  for (int ff = 0; ff < 4; ++ff)
#pragma unroll
    for (int r = 0; r < 4; ++r)
      crow[ff][r] = comp[ff * NTOK + qrow0 + g * 4 + r];

  const unsigned short* kb = qkvh + ((size_t)(f * NTOK)) * NQKV + DIN + h * HD;
  const unsigned short* vb = vTh + ((size_t)(f * DIN + h * HD)) * NTOK;

  const int remK = w * 64 + lane;
  const int ktok = remK >> 3, kdg = remK & 7;
  const int ksw = kdg ^ (ktok & 7);

  auto stageK_to = [&](unsigned short (*dst)[4096], int s) {
#pragma unroll
    for (int j = 0; j < 2; ++j) {
      int tokg = j * 512 + s * 64 + ktok;
      gl_lds16(kb + (size_t)tokg * NQKV + ksw * 8, &dst[j][(w * 64) * 8]);
    }
  };
  auto stageV_to = [&](int s) {
#pragma unroll
    for (int j = 0; j < 2; ++j) {
      int d = ktok, tg = kdg;
      int sw = tg ^ (d & 7);
      gl_lds16(vb + (size_t)d * NTOK + j * 512 + s * 64 + sw * 8, &sV[j][(w * 64) * 8]);
    }
  };

  // ---- pass A: lsum = sum(exp2(S')) over this wave's col half (ping-pong dbuf) ----
  float lsum[4] = {0.f, 0.f, 0.f, 0.f};
  stageK_to(sK, 0);
  __syncthreads();
  for (int s = 0; s < 8; ++s) {
    unsigned short (*cur)[4096] = (s & 1) ? sV : sK;
    if (s < 7) stageK_to((s & 1) ? sK : sV, s + 1);
    bf16x8 bk[4][2];
#pragma unroll
    for (int cf = 0; cf < 4; ++cf)
#pragma unroll
      for (int ks = 0; ks < 2; ++ks) {
        int tok = cf * 16 + li, dg = ks * 4 + g;
        bk[cf][ks] = *reinterpret_cast<const bf16x8*>(&cur[ch][(tok * 8 + (dg ^ (tok & 7))) * 8]);
      }
    f32x4 accs[4];
#pragma unroll
    for (int cf = 0; cf < 4; ++cf) accs[cf] = (f32x4){0.f, 0.f, 0.f, 0.f};
#pragma unroll
    for (int ks = 0; ks < 2; ++ks)
#pragma unroll
      for (int cf = 0; cf < 4; ++cf)
        accs[cf] = __builtin_amdgcn_mfma_f32_16x16x32_bf16(aq[ks], bk[cf][ks], accs[cf], 0, 0, 0);
#pragma unroll
    for (int cf = 0; cf < 4; ++cf)
#pragma unroll
      for (int r = 0; r < 4; ++r) lsum[r] += __builtin_amdgcn_exp2f(accs[cf][r]);
    __syncthreads();
  }
#pragma unroll
  for (int r = 0; r < 4; ++r) {
    lsum[r] += __shfl_xor(lsum[r], 1);
    lsum[r] += __shfl_xor(lsum[r], 2);
    lsum[r] += __shfl_xor(lsum[r], 4);
    lsum[r] += __shfl_xor(lsum[r], 8);
  }
  if (li == 0) {
#pragma unroll
    for (int r = 0; r < 4; ++r) lred[ch][rt][g * 4 + r] = lsum[r];
  }
  __syncthreads();
  float invl[4];
#pragma unroll
  for (int r = 0; r < 4; ++r)
    invl[r] = LOG2E / (lred[0][rt][g * 4 + r] + lred[1][rt][g * 4 + r]);

  // ---- pass B: t = exp2((exp2(S')*invl)*cc), PV + sum2 (stage-after-use) ----
  f32x4 acco[4];
  float sum2[4] = {0.f, 0.f, 0.f, 0.f};
#pragma unroll
  for (int cf = 0; cf < 4; ++cf) acco[cf] = (f32x4){0.f, 0.f, 0.f, 0.f};
  unsigned short* wb = wbuf_all[w];

  stageK_to(sK, 0);
  stageV_to(0);
  __syncthreads();
  for (int s = 0; s < 8; ++s) {
    bf16x8 bk[4][2];
#pragma unroll
    for (int cf = 0; cf < 4; ++cf)
#pragma unroll
      for (int ks = 0; ks < 2; ++ks) {
        int tok = cf * 16 + li, dg = ks * 4 + g;
        bk[cf][ks] = *reinterpret_cast<const bf16x8*>(&sK[ch][(tok * 8 + (dg ^ (tok & 7))) * 8]);
      }
    f32x4 accs[4];
#pragma unroll
    for (int cf = 0; cf < 4; ++cf) accs[cf] = (f32x4){0.f, 0.f, 0.f, 0.f};
#pragma unroll
    for (int ks = 0; ks < 2; ++ks)
#pragma unroll
      for (int cf = 0; cf < 4; ++cf)
        accs[cf] = __builtin_amdgcn_mfma_f32_16x16x32_bf16(aq[ks], bk[cf][ks], accs[cf], 0, 0, 0);
#pragma unroll
    for (int cf = 0; cf < 4; ++cf) {
      int colg = ch * 512 + s * 64 + cf * 16 + li;
      unsigned int u01 = sc01[colg], u23 = sc23[colg];
      float c0 = asf(u01 << 16), c1 = asf(u01 & 0xffff0000u);
      float c2 = asf(u23 << 16), c3 = asf(u23 & 0xffff0000u);
#pragma unroll
      for (int r = 0; r < 4; ++r) {
        float e = __builtin_amdgcn_exp2f(accs[cf][r]);
        float a = e * invl[r];
        float cc = crow[0][r] * c0 + crow[1][r] * c1 + crow[2][r] * c2 + crow[3][r] * c3;
        float tv = __builtin_amdgcn_exp2f(a * cc);
        unsigned short hv = f2b(tv);
        sum2[r] += b2f(hv);
        wb[(g * 4 + r) * 68 + cf * 16 + li] = hv;
      }
    }
    bf16x8 aw[2], bv[4][2];
#pragma unroll
    for (int ks = 0; ks < 2; ++ks)
      aw[ks] = *reinterpret_cast<const bf16x8*>(&wb[li * 68 + ks * 32 + g * 8]);
#pragma unroll
    for (int cf = 0; cf < 4; ++cf)
#pragma unroll
      for (int ks = 0; ks < 2; ++ks) {
        int d = cf * 16 + li, tg = ks * 4 + g;
        bv[cf][ks] = *reinterpret_cast<const bf16x8*>(&sV[ch][(d * 8 + (tg ^ (d & 7))) * 8]);
      }
#pragma unroll
    for (int ks = 0; ks < 2; ++ks)
#pragma unroll
      for (int cf = 0; cf < 4; ++cf)
        acco[cf] = __builtin_amdgcn_mfma_f32_16x16x32_bf16(aw[ks], bv[cf][ks], acco[cf], 0, 0, 0);
    __syncthreads();            // all reads of sK/sV for tile s done
    if (s < 7) { stageK_to(sK, s + 1); stageV_to(s + 1); }
    __syncthreads();            // staged tile s+1 visible
  }

  // ---- combine across ch, write ym ----
#pragma unroll
  for (int r = 0; r < 4; ++r) {
    sum2[r] += __shfl_xor(sum2[r], 1);
    sum2[r] += __shfl_xor(sum2[r], 2);
    sum2[r] += __shfl_xor(sum2[r], 4);
    sum2[r] += __shfl_xor(sum2[r], 8);
  }
  float* fred = (float*)sK;  // 16 KB reuse
  __syncthreads();
  if (ch == 1) {
    if (li == 0) {
#pragma unroll
      for (int r = 0; r < 4; ++r) s2red[rt][g * 4 + r] = sum2[r];
    }
#pragma unroll
    for (int cf = 0; cf < 4; ++cf)
#pragma unroll
      for (int r = 0; r < 4; ++r)
        fred[rt * 1024 + (g * 4 + r) * 64 + cf * 16 + li] = acco[cf][r];
  }
  __syncthreads();
  if (ch == 0) {
    float invs[4];
#pragma unroll
    for (int r = 0; r < 4; ++r) invs[r] = 1.f / (sum2[r] + s2red[rt][g * 4 + r]);
    float cscale[4];
#pragma unroll
    for (int cf = 0; cf < 4; ++cf) cscale[cf] = cmp_[f * DIN + h * HD + cf * 16 + li];
#pragma unroll
    for (int cf = 0; cf < 4; ++cf)
#pragma unroll
      for (int r = 0; r < 4; ++r) {
        float v = (acco[cf][r] + fred[rt * 1024 + (g * 4 + r) * 64 + cf * 16 + li]) * invs[r];
        int qrow = qrow0 + g * 4 + r;
        ym[((size_t)(f * NTOK + qrow)) * DIN + h * HD + cf * 16 + li] = f2b(v * cscale[cf]);
      }
  }
}

extern "C" void kernel_launch(void* const* d_in, const int* in_sizes, int n_in,
                              void* d_out, int out_size, void* d_ws, size_t ws_size,
                              hipStream_t stream) {
  const float* x      = (const float*)d_in[0];
  const float* compat = (const float*)d_in[1];
  const float* code   = (const float*)d_in[2];
  const float* w_c    = (const float*)d_in[3];
  const float* W_qkv  = (const float*)d_in[4];
  const float* b_qkv  = (const float*)d_in[5];
  const float* W_proj = (const float*)d_in[6];
  const float* b_proj = (const float*)d_in[7];
  const float* lnqg   = (const float*)d_in[8];
  const float* lnqb   = (const float*)d_in[9];
  const float* lnpg   = (const float*)d_in[10];
  const float* lnpb   = (const float*)d_in[11];
  float* out = (float*)d_out;

  float* tmpv = (float*)d_ws;                     // 2048
  float* pS   = tmpv + NF * DIN;                  // 32
  float* pQ   = pS + 32;                          // 32
  float* cmp_ = pQ + 32;                          // 2048
  unsigned short* Wqh  = (unsigned short*)(cmp_ + NF * DIN);
  unsigned short* Wph  = Wqh + (size_t)NQKV * DIN;
  unsigned short* xm   = Wph + (size_t)DIN * DIN;
  unsigned short* qkvh = xm + (size_t)NF * NTOK * DIN;
  unsigned short* vTh  = qkvh + (size_t)NF * NTOK * NQKV;
  unsigned short* ym   = vTh + (size_t)NF * DIN * NTOK;

  prep_mv<<<8, 256, 0, stream>>>(w_c, code, tmpv, pS, pQ);
  prep_x<<<769, 256, 0, stream>>>(W_qkv, W_proj, x, tmpv, pS, pQ,
                                  lnqg, lnqb, lnpg, lnpb, Wqh, Wph, xm, cmp_);
  gemm64<NQKV, true, true, true><<<dim3(24, 64), 256, 0, stream>>>(
      xm, Wqh, b_qkv, qkvh, nullptr, vTh);
  attn_mfma4<<<dim3(32, 16), 512, 0, stream>>>(qkvh, vTh, compat, cmp_, ym);
  gemm64<DIN, false, false, false><<<dim3(8, 64), 256, 0, stream>>>(
      ym, Wph, b_proj, nullptr, out, nullptr);
}